// Round 13
// baseline (247.899 us; speedup 1.0000x reference)
//
#include <hip/hip_runtime.h>
#include <cstddef>

#define HD 128   // hidden dim
#define NREL 65
#define SCB 1024 // scan block width
#define NTB ((2 * NREL + 2) * 16)   // transpose-cast blocks in prep_all = 2112

typedef __attribute__((ext_vector_type(8))) short bf16x8;
typedef __attribute__((ext_vector_type(4))) float f32x4;
#define MFMA_BF16(a, b, c) __builtin_amdgcn_mfma_f32_16x16x32_bf16(a, b, c, 0, 0, 0)

__device__ __forceinline__ unsigned short f2bf(float f) {   // RNE f32->bf16
  unsigned int u = __float_as_uint(f);
  u += 0x7FFFu + ((u >> 16) & 1u);
  return (unsigned short)(u >> 16);
}
__device__ __forceinline__ float bf2f(unsigned short u) {
  return __uint_as_float((unsigned int)u << 16);
}
__device__ __forceinline__ float reluf(float v) { return v > 0.f ? v : 0.f; }

// ---------------- fused prep: W transposes-casts + flat casts, one kernel ----------------
struct PrepArgs {
  const float* W1; const float* W2; const float* lw1; const float* lw2;
  unsigned short *W1t, *W2t, *l1t, *l2t;
  const float* csrc[6];
  unsigned short* cdst[6];
  int cn4[6];
  int total4;
};
__global__ void prep_all(PrepArgs a) {
  __shared__ float t[32][33];
  int b = blockIdx.x;
  if (b < NTB) {
    int z = b >> 4, tile = b & 15;
    const float* in; unsigned short* out;
    if (z < NREL)           { in = a.W1 + (size_t)z * HD * HD;          out = a.W1t + (size_t)z * HD * HD; }
    else if (z < 2 * NREL)  { in = a.W2 + (size_t)(z - NREL) * HD * HD; out = a.W2t + (size_t)(z - NREL) * HD * HD; }
    else if (z == 2 * NREL) { in = a.lw1; out = a.l1t; }
    else                    { in = a.lw2; out = a.l2t; }
    int k0 = (tile >> 2) * 32, n0 = (tile & 3) * 32;
    int tx = threadIdx.x & 31, ty = threadIdx.x >> 5;
#pragma unroll
    for (int it = 0; it < 4; ++it)
      t[ty + it * 8][tx] = in[(size_t)(k0 + ty + it * 8) * HD + n0 + tx];
    __syncthreads();
#pragma unroll
    for (int it = 0; it < 4; ++it)
      out[(size_t)(n0 + ty + it * 8) * HD + k0 + tx] = f2bf(t[tx][ty + it * 8]);
  } else {
    int i = (b - NTB) * 256 + threadIdx.x;
    if (i >= a.total4) return;
    int base = 0, s = -1, j = 0;
#pragma unroll
    for (int k = 0; k < 6; ++k) {
      if (s < 0 && i < base + a.cn4[k]) { s = k; j = i - base; }
      base += a.cn4[k];
    }
    float4 v = ((const float4*)a.csrc[s])[j];
    ushort4 o;
    o.x = f2bf(v.x); o.y = f2bf(v.y); o.z = f2bf(v.z); o.w = f2bf(v.w);
    ((ushort4*)a.cdst[s])[j] = o;
  }
}

// ---------------- fused histograms: rel (LDS-agg), dst, motif ----------------
__global__ void hist_all(const int* __restrict__ et, const int* __restrict__ dst,
                         const int* __restrict__ mid, int* __restrict__ rcounts,
                         int* __restrict__ dcount, int* __restrict__ mcount, int E, int N) {
  __shared__ int lc[NREL];
  int tid = threadIdx.x;
  if (tid < NREL) lc[tid] = 0;
  __syncthreads();
  int i = blockIdx.x * blockDim.x + tid;
  if (i < E) {
    atomicAdd(&lc[et[i]], 1);
    atomicAdd(&dcount[dst[i]], 1);
  } else if (i < E + N) {
    atomicAdd(&mcount[mid[i - E]], 1);
  }
  __syncthreads();
  if (tid < NREL && lc[tid] > 0) atomicAdd(&rcounts[tid], lc[tid]);
}

// ---------------- unified scan: job 0 = dst CSR offs, job 1 = motif CSR offs, job 2 = rel ----
__global__ void scan_all(const int* __restrict__ rcounts, int* __restrict__ roffs,
                         const int* __restrict__ dcount, int* __restrict__ doffs, int n0,
                         const int* __restrict__ mcount, int* __restrict__ moffs, int n1) {
  int job = blockIdx.x;
  if (job == 2) {
    if (threadIdx.x == 0) {
      int o = 0;
      for (int r = 0; r < NREL; ++r) { roffs[r] = o; o += (rcounts[r] + 63) & ~63; }
      roffs[NREL] = o;
    }
    return;
  }
  const int* cnt = job ? mcount : dcount;
  int* o = job ? moffs : doffs;
  int n = job ? n1 : n0;
  int CH = (n + SCB - 1) / SCB;
  int t0 = threadIdx.x * CH;
  int s = 0;
  for (int k = 0; k < CH; ++k) { int idx = t0 + k; if (idx < n) s += cnt[idx]; }
  __shared__ int tl[SCB];
  tl[threadIdx.x] = s;
  __syncthreads();
  for (int d = 1; d < SCB; d <<= 1) {
    int x = (threadIdx.x >= d) ? tl[threadIdx.x - d] : 0;
    __syncthreads();
    tl[threadIdx.x] += x;
    __syncthreads();
  }
  int run = tl[threadIdx.x] - s;     // exclusive prefix of this thread's chunk
  for (int k = 0; k < CH; ++k) {
    int idx = t0 + k;
    if (idx < n) { o[idx] = run; run += cnt[idx]; }
  }
}

// ------- fused scatter: edges (rel slot + dst-CSR pos), nodes (motif-CSR + graph ranges) ------
__global__ void scatter_all(const int* __restrict__ src, const int* __restrict__ dst,
                            const int* __restrict__ et, const int* __restrict__ mid,
                            const int* __restrict__ gid,
                            const int* __restrict__ offs, int* __restrict__ cursor,
                            const int* __restrict__ doffs, int* __restrict__ dcursor,
                            const int* __restrict__ moffs, int* __restrict__ mcursor,
                            int* __restrict__ ssrc, int* __restrict__ chunk_rel,
                            int* __restrict__ sdpos, int* __restrict__ nidx,
                            int* __restrict__ gstart, int E, int N, int NGc) {
  __shared__ int lc[NREL];
  __shared__ int lbase[NREL];
  int tid = threadIdx.x;
  if (tid < NREL) lc[tid] = 0;
  __syncthreads();
  int i = blockIdx.x * blockDim.x + tid;
  int r = -1, lrank = 0;
  if (i < E) { r = et[i]; lrank = atomicAdd(&lc[r], 1); }
  __syncthreads();
  if (tid < NREL && lc[tid] > 0) lbase[tid] = atomicAdd(&cursor[tid], lc[tid]);
  __syncthreads();
  if (i < E) {
    int slot = offs[r] + lbase[r] + lrank;
    ssrc[slot] = src[i];
    chunk_rel[slot >> 6] = r;
    int d = dst[i];
    sdpos[slot] = doffs[d] + atomicAdd(&dcursor[d], 1);   // dst-CSR position
  } else if (i < E + N) {
    int node = i - E;
    int m = mid[node];
    int mpos = moffs[m] + atomicAdd(&mcursor[m], 1);
    nidx[mpos] = node;
    // graph ranges from sorted gids: gstart[g] = first node with gid >= g
    int gcur = gid[node];
    int gprev = (node == 0) ? -1 : gid[node - 1];
    for (int g = gprev + 1; g <= gcur; ++g) gstart[g] = node;
    if (node == N - 1)
      for (int g = gcur + 1; g <= NGc; ++g) gstart[g] = N;
  }
}

// ---------------- edge message GEMM -> bf16 stores at dst-CSR positions ----------------
// grid (NCH, 2): x = 64-edge chunk (single relation), y = 64-col half.
__global__ __launch_bounds__(256, 8) void edge_gemm_msg(
    const unsigned short* __restrict__ xb, const unsigned short* __restrict__ Wt,
    const int* __restrict__ ssrc, const int* __restrict__ sdpos,
    const int* __restrict__ chunk_rel, unsigned short* __restrict__ msg) {
  int chunk = blockIdx.x;
  int rel = chunk_rel[chunk];
  if (rel < 0) return;
  int half = blockIdx.y;

  __shared__ __align__(16) unsigned short Ws[64][136];

  int tid = threadIdx.x;
  int lane = tid & 63, w = tid >> 6;
  int l15 = lane & 15, kg = lane >> 4;
  int base = chunk * 64;

  int srow = ssrc[base + w * 16 + l15];
  int dpos[4];
#pragma unroll
  for (int reg = 0; reg < 4; ++reg) dpos[reg] = sdpos[base + w * 16 + kg * 4 + reg];

  const unsigned short* Wr = Wt + (size_t)rel * HD * HD + (size_t)half * 64 * HD;
#pragma unroll
  for (int it = 0; it < 4; ++it) {
    int idx = it * 2048 + tid * 8;
    *(bf16x8*)&Ws[idx >> 7][idx & 127] = *(const bf16x8*)(Wr + idx);
  }

  bf16x8 afr[4];
  const bf16x8 zb = {0, 0, 0, 0, 0, 0, 0, 0};
  if (srow >= 0) {
    const unsigned short* xr = xb + (size_t)srow * HD + kg * 8;
#pragma unroll
    for (int t = 0; t < 4; ++t) afr[t] = *(const bf16x8*)(xr + t * 32);
  } else {
#pragma unroll
    for (int t = 0; t < 4; ++t) afr[t] = zb;
  }
  __syncthreads();

  f32x4 acc[4];
  const f32x4 zf = {0.f, 0.f, 0.f, 0.f};
#pragma unroll
  for (int c = 0; c < 4; ++c) acc[c] = zf;
#pragma unroll
  for (int t = 0; t < 4; ++t)
#pragma unroll
    for (int c = 0; c < 4; ++c) {
      bf16x8 bfr = *(const bf16x8*)&Ws[c * 16 + l15][t * 32 + kg * 8];
      acc[c] = MFMA_BF16(afr[t], bfr, acc[c]);
    }

  // D: row(edge) = kg*4 + reg, col = half*64 + c*16 + l15; store at dst-CSR row
#pragma unroll
  for (int reg = 0; reg < 4; ++reg) {
    if (dpos[reg] >= 0) {
      unsigned short* mp = msg + (size_t)dpos[reg] * HD + half * 64 + l15;
#pragma unroll
      for (int c = 0; c < 4; ++c) mp[c * 16] = f2bf(acc[c][reg]);
    }
  }
}

// ---------------- generic NT GEMM (MFMA bf16): C = epi( A[M,K] @ B[N,K]^T ) ----------------
// EPI 0: +bias; 1: relu(+bias); 2 (DUAL): relu(acc1+b1+GATHER(msg,row)) + relu(acc2+b2),
//   where GATHER sums the row's dst-CSR-contiguous bf16 message rows; + BN colsum atomics.
template<bool DUAL, int EPI, bool OBF16>
__global__ __launch_bounds__(256) void gemm_mfma(
    const unsigned short* __restrict__ A, const unsigned short* __restrict__ B1,
    const unsigned short* __restrict__ B2, const float* __restrict__ bias1,
    const float* __restrict__ bias2,
    const unsigned short* __restrict__ msgp, const int* __restrict__ gdoffs,
    const int* __restrict__ gdcount,
    float* __restrict__ Cf, unsigned short* __restrict__ Cb,
    float* __restrict__ colsum, int M, int N, int K) {
  __shared__ __align__(16) unsigned short As[64][40];
  __shared__ __align__(16) unsigned short B1s[64][40];
  __shared__ __align__(16) unsigned short B2s[DUAL ? 64 : 1][40];
  __shared__ float cs[2][64];

  int tid = threadIdx.x;
  int lane = tid & 63, w = tid >> 6;
  int wr = w >> 1, wc = w & 1;
  int l15 = lane & 15, kg = lane >> 4;
  int row0 = blockIdx.y * 64, col0 = blockIdx.x * 64;
  int srow = tid >> 2, skc = (tid & 3) * 8;

  f32x4 acc1[2][2], acc2[2][2];
  const f32x4 zf = {0.f, 0.f, 0.f, 0.f};
  const bf16x8 zb = {0, 0, 0, 0, 0, 0, 0, 0};
#pragma unroll
  for (int i = 0; i < 2; ++i)
#pragma unroll
    for (int j = 0; j < 2; ++j) { acc1[i][j] = zf; acc2[i][j] = zf; }

  for (int k0 = 0; k0 < K; k0 += 32) {
    {
      int gr = row0 + srow;
      bf16x8 v = zb;
      if (gr < M) v = *(const bf16x8*)(A + (size_t)gr * K + k0 + skc);
      *(bf16x8*)&As[srow][skc] = v;
      *(bf16x8*)&B1s[srow][skc] = *(const bf16x8*)(B1 + (size_t)(col0 + srow) * K + k0 + skc);
      if constexpr (DUAL)
        *(bf16x8*)&B2s[srow][skc] = *(const bf16x8*)(B2 + (size_t)(col0 + srow) * K + k0 + skc);
    }
    __syncthreads();
    bf16x8 af[2], b1f[2];
#pragma unroll
    for (int i = 0; i < 2; ++i) af[i] = *(const bf16x8*)&As[wr * 32 + i * 16 + l15][kg * 8];
#pragma unroll
    for (int j = 0; j < 2; ++j) b1f[j] = *(const bf16x8*)&B1s[wc * 32 + j * 16 + l15][kg * 8];
#pragma unroll
    for (int i = 0; i < 2; ++i)
#pragma unroll
      for (int j = 0; j < 2; ++j) acc1[i][j] = MFMA_BF16(af[i], b1f[j], acc1[i][j]);
    if constexpr (DUAL) {
      bf16x8 b2f[2];
#pragma unroll
      for (int j = 0; j < 2; ++j) b2f[j] = *(const bf16x8*)&B2s[wc * 32 + j * 16 + l15][kg * 8];
#pragma unroll
      for (int i = 0; i < 2; ++i)
#pragma unroll
        for (int j = 0; j < 2; ++j) acc2[i][j] = MFMA_BF16(af[i], b2f[j], acc2[i][j]);
    }
    __syncthreads();
  }

  float s[2] = {0.f, 0.f}, sq[2] = {0.f, 0.f};
#pragma unroll
  for (int i = 0; i < 2; ++i)
#pragma unroll
    for (int reg = 0; reg < 4; ++reg) {
      int row = row0 + wr * 32 + i * 16 + kg * 4 + reg;
      if (row < M) {
        float g[2] = {0.f, 0.f};
        if constexpr (EPI == 2) {
          int gb = gdoffs[row], gd = gdcount[row];
          const unsigned short* mp = msgp + (size_t)gb * HD + col0 + wc * 32 + l15;
          for (int e = 0; e < gd; ++e, mp += HD) {
            g[0] += bf2f(mp[0]);
            g[1] += bf2f(mp[16]);
          }
        }
#pragma unroll
        for (int j = 0; j < 2; ++j) {
          int col = col0 + wc * 32 + j * 16 + l15;
          float v = acc1[i][j][reg];
          if constexpr (EPI == 2) {
            v = reluf(v + bias1[col] + g[j]) + reluf(acc2[i][j][reg] + bias2[col]);
            Cf[(size_t)row * N + col] = v;
            s[j] += v; sq[j] += v * v;
          } else {
            v += bias1[col];
            if constexpr (EPI == 1) v = reluf(v);
            if constexpr (OBF16) Cb[(size_t)row * N + col] = f2bf(v);
            else Cf[(size_t)row * N + col] = v;
          }
        }
      }
    }
  if constexpr (EPI == 2) {
    __syncthreads();
    if (tid < 128) ((float*)cs)[tid] = 0.f;
    __syncthreads();
#pragma unroll
    for (int j = 0; j < 2; ++j) {
      int lc = wc * 32 + j * 16 + l15;
      atomicAdd(&cs[0][lc], s[j]);
      atomicAdd(&cs[1][lc], sq[j]);
    }
    __syncthreads();
    if (tid < 64) {
      atomicAdd(&colsum[col0 + tid], cs[0][tid]);
      atomicAdd(&colsum[HD + col0 + tid], cs[1][tid]);
    }
  }
}

// ---------------- BatchNorm apply (layer 1 only: writes bf16 h for next layer) ----------------
__global__ void bn_apply_bf16(const float* __restrict__ h, unsigned short* __restrict__ hb,
                              const float* __restrict__ colsum, const float* __restrict__ gamma,
                              const float* __restrict__ beta, int M) {
  int i = blockIdx.x * blockDim.x + threadIdx.x;
  if (i >= M * (HD / 4)) return;
  int c0 = (i & 31) * 4;
  float invM = 1.f / (float)M;
  float4 v = ((const float4*)h)[i];
  float r[4] = {v.x, v.y, v.z, v.w};
#pragma unroll
  for (int j = 0; j < 4; ++j) {
    int c = c0 + j;
    float mu = colsum[c] * invM;
    float var = colsum[HD + c] * invM - mu * mu;
    r[j] = (r[j] - mu) * rsqrtf(var + 1e-5f) * gamma[c] + beta[c];
  }
  ushort4 o;
  o.x = f2bf(r[0]); o.y = f2bf(r[1]); o.z = f2bf(r[2]); o.w = f2bf(r[3]);
  ((ushort4*)hb)[i] = o;
}

// --------- unified readout: graph contiguous-range mean + motif CSR mean, + BN affine ---------
// rows [0,NG): graphs via gstart ranges (sorted gids); rows [NG,NG+NM): motifs via CSR.
__global__ __launch_bounds__(256) void readout_norm(
    const float* __restrict__ h, const int* __restrict__ gstart,
    const int* __restrict__ nidx, const int* __restrict__ moffs,
    const int* __restrict__ mcount,
    const float* __restrict__ colsum, const float* __restrict__ gamma,
    const float* __restrict__ beta, float invM,
    float* __restrict__ out_gf, unsigned short* __restrict__ headin, int NGr, int NMr) {
  int row = blockIdx.x * 2 + (threadIdx.x >> 7);
  if (row >= NGr + NMr) return;
  int c = threadIdx.x & 127;
  float mu = colsum[c] * invM;
  float var = colsum[HD + c] * invM - mu * mu;
  float sc = gamma[c] * rsqrtf(var + 1e-5f);
  float sh = beta[c] - mu * sc;
  if (row < NGr) {
    int b = gstart[row], e2 = gstart[row + 1];
    float acc = 0.f;
    for (int n = b; n < e2; ++n) acc += h[(size_t)n * HD + c];
    float v = (e2 > b) ? (acc / (float)(e2 - b)) * sc + sh : 0.f;
    out_gf[(size_t)row * HD + c] = v;
    headin[(size_t)row * HD + c] = f2bf(v);
  } else {
    int m = row - NGr;
    int deg = mcount[m], base = moffs[m];
    float acc = 0.f;
    for (int j = 0; j < deg; ++j) acc += h[(size_t)nidx[base + j] * HD + c];
    float v = (deg > 0) ? (acc / (float)deg) * sc + sh : 0.f;
    if (m > 0) headin[(size_t)(NGr + m - 1) * HD + c] = f2bf(v);
  }
}

extern "C" void kernel_launch(void* const* d_in, const int* in_sizes, int n_in,
                              void* d_out, int out_size, void* d_ws, size_t ws_size,
                              hipStream_t stream) {
  const float* x0     = (const float*)d_in[0];
  const int*   src    = (const int*)d_in[1];
  const int*   dst    = (const int*)d_in[2];
  const int*   etype  = (const int*)d_in[3];
  const int*   gids   = (const int*)d_in[4];
  const int*   mids   = (const int*)d_in[5];
  const float* W1     = (const float*)d_in[6];
  const float* loopW1 = (const float*)d_in[7];
  const float* b1     = (const float*)d_in[8];
  const float* resW1  = (const float*)d_in[9];
  const float* resb1  = (const float*)d_in[10];
  const float* g1     = (const float*)d_in[11];
  const float* be1    = (const float*)d_in[12];
  const float* W2     = (const float*)d_in[13];
  const float* loopW2 = (const float*)d_in[14];
  const float* b2     = (const float*)d_in[15];
  const float* resW2  = (const float*)d_in[16];
  const float* resb2  = (const float*)d_in[17];
  const float* g2     = (const float*)d_in[18];
  const float* be2    = (const float*)d_in[19];
  const float* featW  = (const float*)d_in[20];
  const float* featb  = (const float*)d_in[21];
  const float* mW1    = (const float*)d_in[22];
  const float* mb1    = (const float*)d_in[23];
  const float* mW2    = (const float*)d_in[24];
  const float* mb2    = (const float*)d_in[25];

  const int N = in_sizes[0] / HD;   // 30000
  const int E = in_sizes[1];        // 90000
  const int NG = 1500, NM = 6001, FFN = 512, OUT2 = 256;
  const int NCH = (E + 63) / 64 + NREL;
  const int NHD = N * HD;
  const int NHEAD = NG + NM - 1;    // 7500

  float* ws = (float*)d_ws;
  size_t off = 0;
  auto alloc = [&](size_t n) { float* p = ws + off; off += (n + 63) & ~((size_t)63); return p; };
  float* hbuf  = alloc(NHD);
  unsigned short* msg = (unsigned short*)alloc((size_t)E * HD / 2);  // bf16 msgs, dst-CSR order
  unsigned short* xb    = (unsigned short*)alloc(NHD / 2);
  unsigned short* W1tb  = (unsigned short*)alloc((size_t)NREL * HD * HD / 2);
  unsigned short* W2tb  = (unsigned short*)alloc((size_t)NREL * HD * HD / 2);
  unsigned short* lwT1b = (unsigned short*)alloc(HD * HD / 2);
  unsigned short* lwT2b = (unsigned short*)alloc(HD * HD / 2);
  unsigned short* rW1b  = (unsigned short*)alloc(HD * HD / 2);
  unsigned short* rW2b  = (unsigned short*)alloc(HD * HD / 2);
  unsigned short* featWb= (unsigned short*)alloc(FFN * HD / 2);
  unsigned short* mW1b  = (unsigned short*)alloc(FFN * FFN / 2);
  unsigned short* mW2b  = (unsigned short*)alloc(OUT2 * FFN / 2);
  unsigned short* headin= (unsigned short*)alloc((size_t)NHEAD * HD / 2);
  int* offs   = (int*)alloc(NREL + 1);
  int* doffs  = (int*)alloc(N);
  int* moffs  = (int*)alloc(NM);
  int* nidx   = (int*)alloc(N);
  int* gstart = (int*)alloc(NG + 1);   // fully written by scatter_all
  // ---- zero-init span (ONE memset)
  size_t zero_start = off;
  int* counts  = (int*)alloc(NREL);
  int* cursor  = (int*)alloc(NREL);
  int* dcount  = (int*)alloc(N);
  int* dcursor = (int*)alloc(N);
  int* mcount  = (int*)alloc(NM);
  int* mcursor = (int*)alloc(NM);
  float* colsum1 = alloc(2 * HD);
  float* colsum2 = alloc(2 * HD);
  size_t zero_end = off;
  // ---- 0xFF span (ONE memset): chunk_rel, ssrc, sdpos
  size_t ff_start = off;
  int* chunk_rel = (int*)alloc(NCH);
  int* ssrc      = (int*)alloc((size_t)NCH * 64);
  int* sdpos     = (int*)alloc((size_t)NCH * 64);
  size_t ff_end = off;
  // head intermediates alias msg (dead after layer-2 dual GEMM): 15.4MB < 23MB msg span
  unsigned short* fbuf_b = msg;
  unsigned short* obuf_b = msg + (size_t)NHEAD * FFN;

  float* out_gf = (float*)d_out;
  float* out_gl = out_gf + (size_t)NG * HD;

  dim3 blk(256);

  // ---- one fused prep kernel: transposes + casts ----
  PrepArgs pa{};
  pa.W1 = W1; pa.W2 = W2; pa.lw1 = loopW1; pa.lw2 = loopW2;
  pa.W1t = W1tb; pa.W2t = W2tb; pa.l1t = lwT1b; pa.l2t = lwT2b;
  pa.csrc[0] = x0;    pa.cdst[0] = xb;     pa.cn4[0] = NHD / 4;
  pa.csrc[1] = resW1; pa.cdst[1] = rW1b;   pa.cn4[1] = HD * HD / 4;
  pa.csrc[2] = resW2; pa.cdst[2] = rW2b;   pa.cn4[2] = HD * HD / 4;
  pa.csrc[3] = featW; pa.cdst[3] = featWb; pa.cn4[3] = FFN * HD / 4;
  pa.csrc[4] = mW1;   pa.cdst[4] = mW1b;   pa.cn4[4] = FFN * FFN / 4;
  pa.csrc[5] = mW2;   pa.cdst[5] = mW2b;   pa.cn4[5] = OUT2 * FFN / 4;
  pa.total4 = pa.cn4[0] + pa.cn4[1] + pa.cn4[2] + pa.cn4[3] + pa.cn4[4] + pa.cn4[5];
  int prepBlocks = NTB + (pa.total4 + 255) / 256;
  prep_all<<<prepBlocks, blk, 0, stream>>>(pa);

  // ---- init + CSR build: 2 memsets + 3 kernels ----
  hipMemsetAsync(ws + zero_start, 0, (zero_end - zero_start) * sizeof(float), stream);
  hipMemsetAsync(ws + ff_start, 0xFF, (ff_end - ff_start) * sizeof(float), stream);
  int histBlocks = (E + N + 255) / 256;
  hist_all<<<histBlocks, blk, 0, stream>>>(etype, dst, mids, counts, dcount, mcount, E, N);
  scan_all<<<3, SCB, 0, stream>>>(counts, offs, dcount, doffs, N, mcount, moffs, NM);
  scatter_all<<<histBlocks, blk, 0, stream>>>(src, dst, etype, mids, gids, offs, cursor,
                                              doffs, dcursor, moffs, mcursor,
                                              ssrc, chunk_rel, sdpos, nidx, gstart, E, N, NG);

  dim3 gridDual(HD / 64, (N + 63) / 64);
  dim3 gridEdge(NCH, 2);
  int bnBlocks = (N * (HD / 4) + 255) / 256;

  // ---------------- layer 1 (gather fused into dual GEMM epilogue) ----------------
  edge_gemm_msg<<<gridEdge, blk, 0, stream>>>(xb, W1tb, ssrc, sdpos, chunk_rel, msg);
  gemm_mfma<true, 2, false><<<gridDual, blk, 0, stream>>>(
      xb, lwT1b, rW1b, b1, resb1, msg, doffs, dcount, hbuf, nullptr, colsum1, N, HD, HD);
  bn_apply_bf16<<<bnBlocks, blk, 0, stream>>>(hbuf, xb, colsum1, g1, be1, N);  // -> h1 bf16

  // ---------------- layer 2 (BN folded into readout_norm) ----------------
  edge_gemm_msg<<<gridEdge, blk, 0, stream>>>(xb, W2tb, ssrc, sdpos, chunk_rel, msg);
  gemm_mfma<true, 2, false><<<gridDual, blk, 0, stream>>>(
      xb, lwT2b, rW2b, b2, resb2, msg, doffs, dcount, hbuf, nullptr, colsum2, N, HD, HD);

  // ---------------- readout (graph ranges + motif CSR, one kernel) ----------------
  float invM = 1.f / (float)N;
  readout_norm<<<(NG + NM + 1) / 2, blk, 0, stream>>>(
      hbuf, gstart, nidx, moffs, mcount, colsum2, g2, be2, invM, out_gf, headin, NG, NM);

  // ---- unified head over 7500 rows (last GEMM writes straight to d_out) ----
  dim3 gA(FFN / 64, (NHEAD + 63) / 64);
  gemm_mfma<false, 0, true><<<gA, blk, 0, stream>>>(
      headin, featWb, nullptr, featb, nullptr, nullptr, nullptr, nullptr, nullptr, fbuf_b, nullptr, NHEAD, FFN, HD);
  gemm_mfma<false, 1, true><<<gA, blk, 0, stream>>>(
      fbuf_b, mW1b, nullptr, mb1, nullptr, nullptr, nullptr, nullptr, nullptr, obuf_b, nullptr, NHEAD, FFN, FFN);
  dim3 gC(OUT2 / 64, (NHEAD + 63) / 64);
  gemm_mfma<false, 0, false><<<gC, blk, 0, stream>>>(
      obuf_b, mW2b, nullptr, mb2, nullptr, nullptr, nullptr, nullptr, out_gl, nullptr, nullptr, NHEAD, OUT2, FFN);
}

// Round 14
// 207.476 us; speedup vs baseline: 1.1948x; 1.1948x over previous
//
#include <hip/hip_runtime.h>
#include <cstddef>

#define HD 128   // hidden dim
#define NREL 65
#define SCB 1024 // scan block width
#define NTB ((2 * NREL + 2) * 16)   // transpose-cast blocks in prep_all = 2112

typedef __attribute__((ext_vector_type(8))) short bf16x8;
typedef __attribute__((ext_vector_type(4))) float f32x4;
#define MFMA_BF16(a, b, c) __builtin_amdgcn_mfma_f32_16x16x32_bf16(a, b, c, 0, 0, 0)

__device__ __forceinline__ unsigned short f2bf(float f) {   // RNE f32->bf16
  unsigned int u = __float_as_uint(f);
  u += 0x7FFFu + ((u >> 16) & 1u);
  return (unsigned short)(u >> 16);
}
__device__ __forceinline__ float bf2f(unsigned short u) {
  return __uint_as_float((unsigned int)u << 16);
}
__device__ __forceinline__ float reluf(float v) { return v > 0.f ? v : 0.f; }

// ---------------- fused prep: W transposes-casts + flat casts, one kernel ----------------
struct PrepArgs {
  const float* W1; const float* W2; const float* lw1; const float* lw2;
  unsigned short *W1t, *W2t, *l1t, *l2t;
  const float* csrc[6];
  unsigned short* cdst[6];
  int cn4[6];
  int total4;
};
__global__ void prep_all(PrepArgs a) {
  __shared__ float t[32][33];
  int b = blockIdx.x;
  if (b < NTB) {
    int z = b >> 4, tile = b & 15;
    const float* in; unsigned short* out;
    if (z < NREL)           { in = a.W1 + (size_t)z * HD * HD;          out = a.W1t + (size_t)z * HD * HD; }
    else if (z < 2 * NREL)  { in = a.W2 + (size_t)(z - NREL) * HD * HD; out = a.W2t + (size_t)(z - NREL) * HD * HD; }
    else if (z == 2 * NREL) { in = a.lw1; out = a.l1t; }
    else                    { in = a.lw2; out = a.l2t; }
    int k0 = (tile >> 2) * 32, n0 = (tile & 3) * 32;
    int tx = threadIdx.x & 31, ty = threadIdx.x >> 5;
#pragma unroll
    for (int it = 0; it < 4; ++it)
      t[ty + it * 8][tx] = in[(size_t)(k0 + ty + it * 8) * HD + n0 + tx];
    __syncthreads();
#pragma unroll
    for (int it = 0; it < 4; ++it)
      out[(size_t)(n0 + ty + it * 8) * HD + k0 + tx] = f2bf(t[tx][ty + it * 8]);
  } else {
    int i = (b - NTB) * 256 + threadIdx.x;
    if (i >= a.total4) return;
    int base = 0, s = -1, j = 0;
#pragma unroll
    for (int k = 0; k < 6; ++k) {
      if (s < 0 && i < base + a.cn4[k]) { s = k; j = i - base; }
      base += a.cn4[k];
    }
    float4 v = ((const float4*)a.csrc[s])[j];
    ushort4 o;
    o.x = f2bf(v.x); o.y = f2bf(v.y); o.z = f2bf(v.z); o.w = f2bf(v.w);
    ((ushort4*)a.cdst[s])[j] = o;
  }
}

// ---------------- fused histograms: rel (LDS-agg), dst, motif ----------------
__global__ void hist_all(const int* __restrict__ et, const int* __restrict__ dst,
                         const int* __restrict__ mid, int* __restrict__ rcounts,
                         int* __restrict__ dcount, int* __restrict__ mcount, int E, int N) {
  __shared__ int lc[NREL];
  int tid = threadIdx.x;
  if (tid < NREL) lc[tid] = 0;
  __syncthreads();
  int i = blockIdx.x * blockDim.x + tid;
  if (i < E) {
    atomicAdd(&lc[et[i]], 1);
    atomicAdd(&dcount[dst[i]], 1);
  } else if (i < E + N) {
    atomicAdd(&mcount[mid[i - E]], 1);
  }
  __syncthreads();
  if (tid < NREL && lc[tid] > 0) atomicAdd(&rcounts[tid], lc[tid]);
}

// ------- parallel scan: y=0 dst bins, y=1 motif bins, y=2 rel offsets (block x=0 only) -------
__global__ void scan_blocks(const int* __restrict__ rcounts, int* __restrict__ roffs,
                            const int* __restrict__ c0, int* __restrict__ o0, int* __restrict__ p0, int n0,
                            const int* __restrict__ c1, int* __restrict__ o1, int* __restrict__ p1, int n1) {
  int job = blockIdx.y;
  if (job == 2) {
    if (blockIdx.x == 0 && threadIdx.x == 0) {
      int o = 0;
      for (int r = 0; r < NREL; ++r) { roffs[r] = o; o += (rcounts[r] + 63) & ~63; }
      roffs[NREL] = o;
    }
    return;
  }
  const int* cnt = job ? c1 : c0; int* offs = job ? o1 : o0; int* part = job ? p1 : p0;
  int n = job ? n1 : n0;
  int b = blockIdx.x;
  if (b * SCB >= n) return;
  __shared__ int t[SCB];
  int i = b * SCB + threadIdx.x;
  int v = (i < n) ? cnt[i] : 0;
  t[threadIdx.x] = v;
  __syncthreads();
  for (int d = 1; d < SCB; d <<= 1) {
    int x = (threadIdx.x >= d) ? t[threadIdx.x - d] : 0;
    __syncthreads();
    t[threadIdx.x] += x;
    __syncthreads();
  }
  if (i < n) offs[i] = t[threadIdx.x] - v;   // exclusive within block
  if (threadIdx.x == SCB - 1) part[b] = t[SCB - 1];
}

// addback with inline partial prefix (each block sums part[0..b), <=30 iters)
__global__ void scan_addback2(int* __restrict__ o0, const int* __restrict__ p0, int n0,
                              int* __restrict__ o1, const int* __restrict__ p1, int n1) {
  int job = blockIdx.y;
  int* o = job ? o1 : o0; const int* p = job ? p1 : p0; int n = job ? n1 : n0;
  __shared__ int pre;
  if (threadIdx.x == 0) {
    int s = 0;
    for (int b = 0; b < (int)blockIdx.x; ++b) s += p[b];
    pre = s;
  }
  __syncthreads();
  int i = blockIdx.x * SCB + threadIdx.x;
  if (i < n) o[i] += pre;
}

// ------- fused scatter: edges (rel slot + dst-CSR pos), nodes (motif-CSR + graph ranges) ------
__global__ void scatter_all(const int* __restrict__ src, const int* __restrict__ dst,
                            const int* __restrict__ et, const int* __restrict__ mid,
                            const int* __restrict__ gid,
                            const int* __restrict__ offs, int* __restrict__ cursor,
                            const int* __restrict__ doffs, int* __restrict__ dcursor,
                            const int* __restrict__ moffs, int* __restrict__ mcursor,
                            int* __restrict__ ssrc, int* __restrict__ chunk_rel,
                            int* __restrict__ sdpos, int* __restrict__ nidx,
                            int* __restrict__ gstart, int E, int N, int NGc) {
  __shared__ int lc[NREL];
  __shared__ int lbase[NREL];
  int tid = threadIdx.x;
  if (tid < NREL) lc[tid] = 0;
  __syncthreads();
  int i = blockIdx.x * blockDim.x + tid;
  int r = -1, lrank = 0;
  if (i < E) { r = et[i]; lrank = atomicAdd(&lc[r], 1); }
  __syncthreads();
  if (tid < NREL && lc[tid] > 0) lbase[tid] = atomicAdd(&cursor[tid], lc[tid]);
  __syncthreads();
  if (i < E) {
    int slot = offs[r] + lbase[r] + lrank;
    ssrc[slot] = src[i];
    chunk_rel[slot >> 6] = r;
    int d = dst[i];
    sdpos[slot] = doffs[d] + atomicAdd(&dcursor[d], 1);   // dst-CSR position
  } else if (i < E + N) {
    int node = i - E;
    int m = mid[node];
    int mpos = moffs[m] + atomicAdd(&mcursor[m], 1);
    nidx[mpos] = node;
    // graph ranges from sorted gids: gstart[g] = first node with gid >= g
    int gcur = gid[node];
    int gprev = (node == 0) ? -1 : gid[node - 1];
    for (int g = gprev + 1; g <= gcur; ++g) gstart[g] = node;
    if (node == N - 1)
      for (int g = gcur + 1; g <= NGc; ++g) gstart[g] = N;
  }
}

// ---------------- edge message GEMM -> bf16 stores at dst-CSR positions ----------------
// grid (NCH, 2): x = 64-edge chunk (single relation), y = 64-col half.
__global__ __launch_bounds__(256, 8) void edge_gemm_msg(
    const unsigned short* __restrict__ xb, const unsigned short* __restrict__ Wt,
    const int* __restrict__ ssrc, const int* __restrict__ sdpos,
    const int* __restrict__ chunk_rel, unsigned short* __restrict__ msg) {
  int chunk = blockIdx.x;
  int rel = chunk_rel[chunk];
  if (rel < 0) return;
  int half = blockIdx.y;

  __shared__ __align__(16) unsigned short Ws[64][136];

  int tid = threadIdx.x;
  int lane = tid & 63, w = tid >> 6;
  int l15 = lane & 15, kg = lane >> 4;
  int base = chunk * 64;

  int srow = ssrc[base + w * 16 + l15];
  int dpos[4];
#pragma unroll
  for (int reg = 0; reg < 4; ++reg) dpos[reg] = sdpos[base + w * 16 + kg * 4 + reg];

  const unsigned short* Wr = Wt + (size_t)rel * HD * HD + (size_t)half * 64 * HD;
#pragma unroll
  for (int it = 0; it < 4; ++it) {
    int idx = it * 2048 + tid * 8;
    *(bf16x8*)&Ws[idx >> 7][idx & 127] = *(const bf16x8*)(Wr + idx);
  }

  bf16x8 afr[4];
  const bf16x8 zb = {0, 0, 0, 0, 0, 0, 0, 0};
  if (srow >= 0) {
    const unsigned short* xr = xb + (size_t)srow * HD + kg * 8;
#pragma unroll
    for (int t = 0; t < 4; ++t) afr[t] = *(const bf16x8*)(xr + t * 32);
  } else {
#pragma unroll
    for (int t = 0; t < 4; ++t) afr[t] = zb;
  }
  __syncthreads();

  f32x4 acc[4];
  const f32x4 zf = {0.f, 0.f, 0.f, 0.f};
#pragma unroll
  for (int c = 0; c < 4; ++c) acc[c] = zf;
#pragma unroll
  for (int t = 0; t < 4; ++t)
#pragma unroll
    for (int c = 0; c < 4; ++c) {
      bf16x8 bfr = *(const bf16x8*)&Ws[c * 16 + l15][t * 32 + kg * 8];
      acc[c] = MFMA_BF16(afr[t], bfr, acc[c]);
    }

  // D: row(edge) = kg*4 + reg, col = half*64 + c*16 + l15; store at dst-CSR row
#pragma unroll
  for (int reg = 0; reg < 4; ++reg) {
    if (dpos[reg] >= 0) {
      unsigned short* mp = msg + (size_t)dpos[reg] * HD + half * 64 + l15;
#pragma unroll
      for (int c = 0; c < 4; ++c) mp[c * 16] = f2bf(acc[c][reg]);
    }
  }
}

// ---------------- generic NT GEMM (MFMA bf16): C = epi( A[M,K] @ B[N,K]^T ) ----------------
// EPI 0: +bias; 1: relu(+bias); 2 (DUAL): relu(acc1+b1+GATHER(msg,row)) + relu(acc2+b2),
//   where GATHER sums the row's dst-CSR-contiguous bf16 message rows; + BN colsum atomics.
template<bool DUAL, int EPI, bool OBF16>
__global__ __launch_bounds__(256) void gemm_mfma(
    const unsigned short* __restrict__ A, const unsigned short* __restrict__ B1,
    const unsigned short* __restrict__ B2, const float* __restrict__ bias1,
    const float* __restrict__ bias2,
    const unsigned short* __restrict__ msgp, const int* __restrict__ gdoffs,
    const int* __restrict__ gdcount,
    float* __restrict__ Cf, unsigned short* __restrict__ Cb,
    float* __restrict__ colsum, int M, int N, int K) {
  __shared__ __align__(16) unsigned short As[64][40];
  __shared__ __align__(16) unsigned short B1s[64][40];
  __shared__ __align__(16) unsigned short B2s[DUAL ? 64 : 1][40];
  __shared__ float cs[2][64];

  int tid = threadIdx.x;
  int lane = tid & 63, w = tid >> 6;
  int wr = w >> 1, wc = w & 1;
  int l15 = lane & 15, kg = lane >> 4;
  int row0 = blockIdx.y * 64, col0 = blockIdx.x * 64;
  int srow = tid >> 2, skc = (tid & 3) * 8;

  f32x4 acc1[2][2], acc2[2][2];
  const f32x4 zf = {0.f, 0.f, 0.f, 0.f};
  const bf16x8 zb = {0, 0, 0, 0, 0, 0, 0, 0};
#pragma unroll
  for (int i = 0; i < 2; ++i)
#pragma unroll
    for (int j = 0; j < 2; ++j) { acc1[i][j] = zf; acc2[i][j] = zf; }

  for (int k0 = 0; k0 < K; k0 += 32) {
    {
      int gr = row0 + srow;
      bf16x8 v = zb;
      if (gr < M) v = *(const bf16x8*)(A + (size_t)gr * K + k0 + skc);
      *(bf16x8*)&As[srow][skc] = v;
      *(bf16x8*)&B1s[srow][skc] = *(const bf16x8*)(B1 + (size_t)(col0 + srow) * K + k0 + skc);
      if constexpr (DUAL)
        *(bf16x8*)&B2s[srow][skc] = *(const bf16x8*)(B2 + (size_t)(col0 + srow) * K + k0 + skc);
    }
    __syncthreads();
    bf16x8 af[2], b1f[2];
#pragma unroll
    for (int i = 0; i < 2; ++i) af[i] = *(const bf16x8*)&As[wr * 32 + i * 16 + l15][kg * 8];
#pragma unroll
    for (int j = 0; j < 2; ++j) b1f[j] = *(const bf16x8*)&B1s[wc * 32 + j * 16 + l15][kg * 8];
#pragma unroll
    for (int i = 0; i < 2; ++i)
#pragma unroll
      for (int j = 0; j < 2; ++j) acc1[i][j] = MFMA_BF16(af[i], b1f[j], acc1[i][j]);
    if constexpr (DUAL) {
      bf16x8 b2f[2];
#pragma unroll
      for (int j = 0; j < 2; ++j) b2f[j] = *(const bf16x8*)&B2s[wc * 32 + j * 16 + l15][kg * 8];
#pragma unroll
      for (int i = 0; i < 2; ++i)
#pragma unroll
        for (int j = 0; j < 2; ++j) acc2[i][j] = MFMA_BF16(af[i], b2f[j], acc2[i][j]);
    }
    __syncthreads();
  }

  float s[2] = {0.f, 0.f}, sq[2] = {0.f, 0.f};
#pragma unroll
  for (int i = 0; i < 2; ++i)
#pragma unroll
    for (int reg = 0; reg < 4; ++reg) {
      int row = row0 + wr * 32 + i * 16 + kg * 4 + reg;
      if (row < M) {
        float g[2] = {0.f, 0.f};
        if constexpr (EPI == 2) {
          int gb = gdoffs[row], gd = gdcount[row];
          const unsigned short* mp = msgp + (size_t)gb * HD + col0 + wc * 32 + l15;
          for (int e = 0; e < gd; ++e, mp += HD) {
            g[0] += bf2f(mp[0]);
            g[1] += bf2f(mp[16]);
          }
        }
#pragma unroll
        for (int j = 0; j < 2; ++j) {
          int col = col0 + wc * 32 + j * 16 + l15;
          float v = acc1[i][j][reg];
          if constexpr (EPI == 2) {
            v = reluf(v + bias1[col] + g[j]) + reluf(acc2[i][j][reg] + bias2[col]);
            Cf[(size_t)row * N + col] = v;
            s[j] += v; sq[j] += v * v;
          } else {
            v += bias1[col];
            if constexpr (EPI == 1) v = reluf(v);
            if constexpr (OBF16) Cb[(size_t)row * N + col] = f2bf(v);
            else Cf[(size_t)row * N + col] = v;
          }
        }
      }
    }
  if constexpr (EPI == 2) {
    __syncthreads();
    if (tid < 128) ((float*)cs)[tid] = 0.f;
    __syncthreads();
#pragma unroll
    for (int j = 0; j < 2; ++j) {
      int lc = wc * 32 + j * 16 + l15;
      atomicAdd(&cs[0][lc], s[j]);
      atomicAdd(&cs[1][lc], sq[j]);
    }
    __syncthreads();
    if (tid < 64) {
      atomicAdd(&colsum[col0 + tid], cs[0][tid]);
      atomicAdd(&colsum[HD + col0 + tid], cs[1][tid]);
    }
  }
}

// ---------------- BatchNorm apply (layer 1 only: writes bf16 h for next layer) ----------------
__global__ void bn_apply_bf16(const float* __restrict__ h, unsigned short* __restrict__ hb,
                              const float* __restrict__ colsum, const float* __restrict__ gamma,
                              const float* __restrict__ beta, int M) {
  int i = blockIdx.x * blockDim.x + threadIdx.x;
  if (i >= M * (HD / 4)) return;
  int c0 = (i & 31) * 4;
  float invM = 1.f / (float)M;
  float4 v = ((const float4*)h)[i];
  float r[4] = {v.x, v.y, v.z, v.w};
#pragma unroll
  for (int j = 0; j < 4; ++j) {
    int c = c0 + j;
    float mu = colsum[c] * invM;
    float var = colsum[HD + c] * invM - mu * mu;
    r[j] = (r[j] - mu) * rsqrtf(var + 1e-5f) * gamma[c] + beta[c];
  }
  ushort4 o;
  o.x = f2bf(r[0]); o.y = f2bf(r[1]); o.z = f2bf(r[2]); o.w = f2bf(r[3]);
  ((ushort4*)hb)[i] = o;
}

// --------- unified readout: graph contiguous-range mean + motif CSR mean, + BN affine ---------
__global__ __launch_bounds__(256) void readout_norm(
    const float* __restrict__ h, const int* __restrict__ gstart,
    const int* __restrict__ nidx, const int* __restrict__ moffs,
    const int* __restrict__ mcount,
    const float* __restrict__ colsum, const float* __restrict__ gamma,
    const float* __restrict__ beta, float invM,
    float* __restrict__ out_gf, unsigned short* __restrict__ headin, int NGr, int NMr) {
  int row = blockIdx.x * 2 + (threadIdx.x >> 7);
  if (row >= NGr + NMr) return;
  int c = threadIdx.x & 127;
  float mu = colsum[c] * invM;
  float var = colsum[HD + c] * invM - mu * mu;
  float sc = gamma[c] * rsqrtf(var + 1e-5f);
  float sh = beta[c] - mu * sc;
  if (row < NGr) {
    int b = gstart[row], e2 = gstart[row + 1];
    float acc = 0.f;
    for (int n = b; n < e2; ++n) acc += h[(size_t)n * HD + c];
    float v = (e2 > b) ? (acc / (float)(e2 - b)) * sc + sh : 0.f;
    out_gf[(size_t)row * HD + c] = v;
    headin[(size_t)row * HD + c] = f2bf(v);
  } else {
    int m = row - NGr;
    int deg = mcount[m], base = moffs[m];
    float acc = 0.f;
    for (int j = 0; j < deg; ++j) acc += h[(size_t)nidx[base + j] * HD + c];
    float v = (deg > 0) ? (acc / (float)deg) * sc + sh : 0.f;
    if (m > 0) headin[(size_t)(NGr + m - 1) * HD + c] = f2bf(v);
  }
}

extern "C" void kernel_launch(void* const* d_in, const int* in_sizes, int n_in,
                              void* d_out, int out_size, void* d_ws, size_t ws_size,
                              hipStream_t stream) {
  const float* x0     = (const float*)d_in[0];
  const int*   src    = (const int*)d_in[1];
  const int*   dst    = (const int*)d_in[2];
  const int*   etype  = (const int*)d_in[3];
  const int*   gids   = (const int*)d_in[4];
  const int*   mids   = (const int*)d_in[5];
  const float* W1     = (const float*)d_in[6];
  const float* loopW1 = (const float*)d_in[7];
  const float* b1     = (const float*)d_in[8];
  const float* resW1  = (const float*)d_in[9];
  const float* resb1  = (const float*)d_in[10];
  const float* g1     = (const float*)d_in[11];
  const float* be1    = (const float*)d_in[12];
  const float* W2     = (const float*)d_in[13];
  const float* loopW2 = (const float*)d_in[14];
  const float* b2     = (const float*)d_in[15];
  const float* resW2  = (const float*)d_in[16];
  const float* resb2  = (const float*)d_in[17];
  const float* g2     = (const float*)d_in[18];
  const float* be2    = (const float*)d_in[19];
  const float* featW  = (const float*)d_in[20];
  const float* featb  = (const float*)d_in[21];
  const float* mW1    = (const float*)d_in[22];
  const float* mb1    = (const float*)d_in[23];
  const float* mW2    = (const float*)d_in[24];
  const float* mb2    = (const float*)d_in[25];

  const int N = in_sizes[0] / HD;   // 30000
  const int E = in_sizes[1];        // 90000
  const int NG = 1500, NM = 6001, FFN = 512, OUT2 = 256;
  const int NCH = (E + 63) / 64 + NREL;
  const int NHD = N * HD;
  const int NHEAD = NG + NM - 1;    // 7500

  float* ws = (float*)d_ws;
  size_t off = 0;
  auto alloc = [&](size_t n) { float* p = ws + off; off += (n + 63) & ~((size_t)63); return p; };
  float* hbuf  = alloc(NHD);
  unsigned short* msg = (unsigned short*)alloc((size_t)E * HD / 2);  // bf16 msgs, dst-CSR order
  unsigned short* xb    = (unsigned short*)alloc(NHD / 2);
  unsigned short* W1tb  = (unsigned short*)alloc((size_t)NREL * HD * HD / 2);
  unsigned short* W2tb  = (unsigned short*)alloc((size_t)NREL * HD * HD / 2);
  unsigned short* lwT1b = (unsigned short*)alloc(HD * HD / 2);
  unsigned short* lwT2b = (unsigned short*)alloc(HD * HD / 2);
  unsigned short* rW1b  = (unsigned short*)alloc(HD * HD / 2);
  unsigned short* rW2b  = (unsigned short*)alloc(HD * HD / 2);
  unsigned short* featWb= (unsigned short*)alloc(FFN * HD / 2);
  unsigned short* mW1b  = (unsigned short*)alloc(FFN * FFN / 2);
  unsigned short* mW2b  = (unsigned short*)alloc(OUT2 * FFN / 2);
  unsigned short* headin= (unsigned short*)alloc((size_t)NHEAD * HD / 2);
  int* offs   = (int*)alloc(NREL + 1);
  int* doffs  = (int*)alloc(N);
  int* moffs  = (int*)alloc(NM);
  int* p0     = (int*)alloc(64);
  int* p1     = (int*)alloc(64);
  int* nidx   = (int*)alloc(N);
  int* gstart = (int*)alloc(NG + 1);   // fully written by scatter_all
  // ---- zero-init span (ONE memset)
  size_t zero_start = off;
  int* counts  = (int*)alloc(NREL);
  int* cursor  = (int*)alloc(NREL);
  int* dcount  = (int*)alloc(N);
  int* dcursor = (int*)alloc(N);
  int* mcount  = (int*)alloc(NM);
  int* mcursor = (int*)alloc(NM);
  float* colsum1 = alloc(2 * HD);
  float* colsum2 = alloc(2 * HD);
  size_t zero_end = off;
  // ---- 0xFF span (ONE memset): chunk_rel, ssrc, sdpos
  size_t ff_start = off;
  int* chunk_rel = (int*)alloc(NCH);
  int* ssrc      = (int*)alloc((size_t)NCH * 64);
  int* sdpos     = (int*)alloc((size_t)NCH * 64);
  size_t ff_end = off;
  // head intermediates alias msg (dead after layer-2 dual GEMM): 15.4MB < 23MB msg span
  unsigned short* fbuf_b = msg;
  unsigned short* obuf_b = msg + (size_t)NHEAD * FFN;

  float* out_gf = (float*)d_out;
  float* out_gl = out_gf + (size_t)NG * HD;

  dim3 blk(256);
  const int nb0 = (N + SCB - 1) / SCB;    // 30
  const int nb1 = (NM + SCB - 1) / SCB;   // 6

  // ---- one fused prep kernel: transposes + casts ----
  PrepArgs pa{};
  pa.W1 = W1; pa.W2 = W2; pa.lw1 = loopW1; pa.lw2 = loopW2;
  pa.W1t = W1tb; pa.W2t = W2tb; pa.l1t = lwT1b; pa.l2t = lwT2b;
  pa.csrc[0] = x0;    pa.cdst[0] = xb;     pa.cn4[0] = NHD / 4;
  pa.csrc[1] = resW1; pa.cdst[1] = rW1b;   pa.cn4[1] = HD * HD / 4;
  pa.csrc[2] = resW2; pa.cdst[2] = rW2b;   pa.cn4[2] = HD * HD / 4;
  pa.csrc[3] = featW; pa.cdst[3] = featWb; pa.cn4[3] = FFN * HD / 4;
  pa.csrc[4] = mW1;   pa.cdst[4] = mW1b;   pa.cn4[4] = FFN * FFN / 4;
  pa.csrc[5] = mW2;   pa.cdst[5] = mW2b;   pa.cn4[5] = OUT2 * FFN / 4;
  pa.total4 = pa.cn4[0] + pa.cn4[1] + pa.cn4[2] + pa.cn4[3] + pa.cn4[4] + pa.cn4[5];
  int prepBlocks = NTB + (pa.total4 + 255) / 256;
  prep_all<<<prepBlocks, blk, 0, stream>>>(pa);

  // ---- init + CSR build: 2 memsets + 4 kernels (parallel scan restored) ----
  hipMemsetAsync(ws + zero_start, 0, (zero_end - zero_start) * sizeof(float), stream);
  hipMemsetAsync(ws + ff_start, 0xFF, (ff_end - ff_start) * sizeof(float), stream);
  int histBlocks = (E + N + 255) / 256;
  hist_all<<<histBlocks, blk, 0, stream>>>(etype, dst, mids, counts, dcount, mcount, E, N);
  scan_blocks<<<dim3(nb0, 3), SCB, 0, stream>>>(counts, offs, dcount, doffs, p0, N,
                                                mcount, moffs, p1, NM);
  scan_addback2<<<dim3(nb0, 2), SCB, 0, stream>>>(doffs, p0, N, moffs, p1, NM);
  scatter_all<<<histBlocks, blk, 0, stream>>>(src, dst, etype, mids, gids, offs, cursor,
                                              doffs, dcursor, moffs, mcursor,
                                              ssrc, chunk_rel, sdpos, nidx, gstart, E, N, NG);

  dim3 gridDual(HD / 64, (N + 63) / 64);
  dim3 gridEdge(NCH, 2);
  int bnBlocks = (N * (HD / 4) + 255) / 256;

  // ---------------- layer 1 (gather fused into dual GEMM epilogue) ----------------
  edge_gemm_msg<<<gridEdge, blk, 0, stream>>>(xb, W1tb, ssrc, sdpos, chunk_rel, msg);
  gemm_mfma<true, 2, false><<<gridDual, blk, 0, stream>>>(
      xb, lwT1b, rW1b, b1, resb1, msg, doffs, dcount, hbuf, nullptr, colsum1, N, HD, HD);
  bn_apply_bf16<<<bnBlocks, blk, 0, stream>>>(hbuf, xb, colsum1, g1, be1, N);  // -> h1 bf16

  // ---------------- layer 2 (BN folded into readout_norm) ----------------
  edge_gemm_msg<<<gridEdge, blk, 0, stream>>>(xb, W2tb, ssrc, sdpos, chunk_rel, msg);
  gemm_mfma<true, 2, false><<<gridDual, blk, 0, stream>>>(
      xb, lwT2b, rW2b, b2, resb2, msg, doffs, dcount, hbuf, nullptr, colsum2, N, HD, HD);

  // ---------------- readout (graph ranges + motif CSR, one kernel) ----------------
  float invM = 1.f / (float)N;
  readout_norm<<<(NG + NM + 1) / 2, blk, 0, stream>>>(
      hbuf, gstart, nidx, moffs, mcount, colsum2, g2, be2, invM, out_gf, headin, NG, NM);

  // ---- unified head over 7500 rows (last GEMM writes straight to d_out) ----
  dim3 gA(FFN / 64, (NHEAD + 63) / 64);
  gemm_mfma<false, 0, true><<<gA, blk, 0, stream>>>(
      headin, featWb, nullptr, featb, nullptr, nullptr, nullptr, nullptr, nullptr, fbuf_b, nullptr, NHEAD, FFN, HD);
  gemm_mfma<false, 1, true><<<gA, blk, 0, stream>>>(
      fbuf_b, mW1b, nullptr, mb1, nullptr, nullptr, nullptr, nullptr, nullptr, obuf_b, nullptr, NHEAD, FFN, FFN);
  dim3 gC(OUT2 / 64, (NHEAD + 63) / 64);
  gemm_mfma<false, 0, false><<<gC, blk, 0, stream>>>(
      obuf_b, mW2b, nullptr, mb2, nullptr, nullptr, nullptr, nullptr, out_gl, nullptr, nullptr, NHEAD, OUT2, FFN);
}

// Round 15
// 187.196 us; speedup vs baseline: 1.3243x; 1.1083x over previous
//
#include <hip/hip_runtime.h>
#include <cstddef>

#define HD 128   // hidden dim
#define NREL 65
#define SCB 1024 // scan block width
#define NTB ((2 * NREL + 2) * 16)   // transpose-cast blocks in prep_all = 2112

typedef __attribute__((ext_vector_type(8))) short bf16x8;
typedef __attribute__((ext_vector_type(4))) float f32x4;
#define MFMA_BF16(a, b, c) __builtin_amdgcn_mfma_f32_16x16x32_bf16(a, b, c, 0, 0, 0)

__device__ __forceinline__ unsigned short f2bf(float f) {   // RNE f32->bf16
  unsigned int u = __float_as_uint(f);
  u += 0x7FFFu + ((u >> 16) & 1u);
  return (unsigned short)(u >> 16);
}
__device__ __forceinline__ float bf2f(unsigned short u) {
  return __uint_as_float((unsigned int)u << 16);
}
__device__ __forceinline__ float reluf(float v) { return v > 0.f ? v : 0.f; }

// ---------------- fused prep: W transposes-casts + flat casts, one kernel ----------------
struct PrepArgs {
  const float* W1; const float* W2; const float* lw1; const float* lw2;
  unsigned short *W1t, *W2t, *l1t, *l2t;
  const float* csrc[6];
  unsigned short* cdst[6];
  int cn4[6];
  int total4;
};
__global__ void prep_all(PrepArgs a) {
  __shared__ float t[32][33];
  int b = blockIdx.x;
  if (b < NTB) {
    int z = b >> 4, tile = b & 15;
    const float* in; unsigned short* out;
    if (z < NREL)           { in = a.W1 + (size_t)z * HD * HD;          out = a.W1t + (size_t)z * HD * HD; }
    else if (z < 2 * NREL)  { in = a.W2 + (size_t)(z - NREL) * HD * HD; out = a.W2t + (size_t)(z - NREL) * HD * HD; }
    else if (z == 2 * NREL) { in = a.lw1; out = a.l1t; }
    else                    { in = a.lw2; out = a.l2t; }
    int k0 = (tile >> 2) * 32, n0 = (tile & 3) * 32;
    int tx = threadIdx.x & 31, ty = threadIdx.x >> 5;
#pragma unroll
    for (int it = 0; it < 4; ++it)
      t[ty + it * 8][tx] = in[(size_t)(k0 + ty + it * 8) * HD + n0 + tx];
    __syncthreads();
#pragma unroll
    for (int it = 0; it < 4; ++it)
      out[(size_t)(n0 + ty + it * 8) * HD + k0 + tx] = f2bf(t[tx][ty + it * 8]);
  } else {
    int i = (b - NTB) * 256 + threadIdx.x;
    if (i >= a.total4) return;
    int base = 0, s = -1, j = 0;
#pragma unroll
    for (int k = 0; k < 6; ++k) {
      if (s < 0 && i < base + a.cn4[k]) { s = k; j = i - base; }
      base += a.cn4[k];
    }
    float4 v = ((const float4*)a.csrc[s])[j];
    ushort4 o;
    o.x = f2bf(v.x); o.y = f2bf(v.y); o.z = f2bf(v.z); o.w = f2bf(v.w);
    ((ushort4*)a.cdst[s])[j] = o;
  }
}

// ---------------- fused histograms: rel (LDS-agg), dst, motif ----------------
__global__ void hist_all(const int* __restrict__ et, const int* __restrict__ dst,
                         const int* __restrict__ mid, int* __restrict__ rcounts,
                         int* __restrict__ dcount, int* __restrict__ mcount, int E, int N) {
  __shared__ int lc[NREL];
  int tid = threadIdx.x;
  if (tid < NREL) lc[tid] = 0;
  __syncthreads();
  int i = blockIdx.x * blockDim.x + tid;
  if (i < E) {
    atomicAdd(&lc[et[i]], 1);
    atomicAdd(&dcount[dst[i]], 1);
  } else if (i < E + N) {
    atomicAdd(&mcount[mid[i - E]], 1);
  }
  __syncthreads();
  if (tid < NREL && lc[tid] > 0) atomicAdd(&rcounts[tid], lc[tid]);
}

// ------- parallel scan: y=0 dst bins, y=1 motif bins, y=2 rel offsets (block x=0 only) -------
__global__ void scan_blocks(const int* __restrict__ rcounts, int* __restrict__ roffs,
                            const int* __restrict__ c0, int* __restrict__ o0, int* __restrict__ p0, int n0,
                            const int* __restrict__ c1, int* __restrict__ o1, int* __restrict__ p1, int n1) {
  int job = blockIdx.y;
  if (job == 2) {
    if (blockIdx.x == 0 && threadIdx.x == 0) {
      int o = 0;
      for (int r = 0; r < NREL; ++r) { roffs[r] = o; o += (rcounts[r] + 63) & ~63; }
      roffs[NREL] = o;
    }
    return;
  }
  const int* cnt = job ? c1 : c0; int* offs = job ? o1 : o0; int* part = job ? p1 : p0;
  int n = job ? n1 : n0;
  int b = blockIdx.x;
  if (b * SCB >= n) return;
  __shared__ int t[SCB];
  int i = b * SCB + threadIdx.x;
  int v = (i < n) ? cnt[i] : 0;
  t[threadIdx.x] = v;
  __syncthreads();
  for (int d = 1; d < SCB; d <<= 1) {
    int x = (threadIdx.x >= d) ? t[threadIdx.x - d] : 0;
    __syncthreads();
    t[threadIdx.x] += x;
    __syncthreads();
  }
  if (i < n) offs[i] = t[threadIdx.x] - v;   // exclusive within block
  if (threadIdx.x == SCB - 1) part[b] = t[SCB - 1];
}

// addback with inline partial prefix (each block sums part[0..b), <=30 iters)
__global__ void scan_addback2(int* __restrict__ o0, const int* __restrict__ p0, int n0,
                              int* __restrict__ o1, const int* __restrict__ p1, int n1) {
  int job = blockIdx.y;
  int* o = job ? o1 : o0; const int* p = job ? p1 : p0; int n = job ? n1 : n0;
  __shared__ int pre;
  if (threadIdx.x == 0) {
    int s = 0;
    for (int b = 0; b < (int)blockIdx.x; ++b) s += p[b];
    pre = s;
  }
  __syncthreads();
  int i = blockIdx.x * SCB + threadIdx.x;
  if (i < n) o[i] += pre;
}

// ------- fused scatter: edges (rel slot + dst-CSR pos), nodes (motif-CSR + graph ranges) ------
__global__ void scatter_all(const int* __restrict__ src, const int* __restrict__ dst,
                            const int* __restrict__ et, const int* __restrict__ mid,
                            const int* __restrict__ gid,
                            const int* __restrict__ offs, int* __restrict__ cursor,
                            const int* __restrict__ doffs, int* __restrict__ dcursor,
                            const int* __restrict__ moffs, int* __restrict__ mcursor,
                            int* __restrict__ ssrc, int* __restrict__ chunk_rel,
                            int* __restrict__ sdpos, int* __restrict__ nidx,
                            int* __restrict__ gstart, int E, int N, int NGc) {
  __shared__ int lc[NREL];
  __shared__ int lbase[NREL];
  int tid = threadIdx.x;
  if (tid < NREL) lc[tid] = 0;
  __syncthreads();
  int i = blockIdx.x * blockDim.x + tid;
  int r = -1, lrank = 0;
  if (i < E) { r = et[i]; lrank = atomicAdd(&lc[r], 1); }
  __syncthreads();
  if (tid < NREL && lc[tid] > 0) lbase[tid] = atomicAdd(&cursor[tid], lc[tid]);
  __syncthreads();
  if (i < E) {
    int slot = offs[r] + lbase[r] + lrank;
    ssrc[slot] = src[i];
    chunk_rel[slot >> 6] = r;
    int d = dst[i];
    sdpos[slot] = doffs[d] + atomicAdd(&dcursor[d], 1);   // dst-CSR position
  } else if (i < E + N) {
    int node = i - E;
    int m = mid[node];
    int mpos = moffs[m] + atomicAdd(&mcursor[m], 1);
    nidx[mpos] = node;
    // graph ranges from sorted gids: gstart[g] = first node with gid >= g
    int gcur = gid[node];
    int gprev = (node == 0) ? -1 : gid[node - 1];
    for (int g = gprev + 1; g <= gcur; ++g) gstart[g] = node;
    if (node == N - 1)
      for (int g = gcur + 1; g <= NGc; ++g) gstart[g] = N;
  }
}

// ---------------- edge message GEMM -> bf16 stores at dst-CSR positions ----------------
// grid (NCH, 2): x = 64-edge chunk (single relation), y = 64-col half.
__global__ __launch_bounds__(256, 8) void edge_gemm_msg(
    const unsigned short* __restrict__ xb, const unsigned short* __restrict__ Wt,
    const int* __restrict__ ssrc, const int* __restrict__ sdpos,
    const int* __restrict__ chunk_rel, unsigned short* __restrict__ msg) {
  int chunk = blockIdx.x;
  int rel = chunk_rel[chunk];
  if (rel < 0) return;
  int half = blockIdx.y;

  __shared__ __align__(16) unsigned short Ws[64][136];

  int tid = threadIdx.x;
  int lane = tid & 63, w = tid >> 6;
  int l15 = lane & 15, kg = lane >> 4;
  int base = chunk * 64;

  int srow = ssrc[base + w * 16 + l15];
  int dpos[4];
#pragma unroll
  for (int reg = 0; reg < 4; ++reg) dpos[reg] = sdpos[base + w * 16 + kg * 4 + reg];

  const unsigned short* Wr = Wt + (size_t)rel * HD * HD + (size_t)half * 64 * HD;
#pragma unroll
  for (int it = 0; it < 4; ++it) {
    int idx = it * 2048 + tid * 8;
    *(bf16x8*)&Ws[idx >> 7][idx & 127] = *(const bf16x8*)(Wr + idx);
  }

  bf16x8 afr[4];
  const bf16x8 zb = {0, 0, 0, 0, 0, 0, 0, 0};
  if (srow >= 0) {
    const unsigned short* xr = xb + (size_t)srow * HD + kg * 8;
#pragma unroll
    for (int t = 0; t < 4; ++t) afr[t] = *(const bf16x8*)(xr + t * 32);
  } else {
#pragma unroll
    for (int t = 0; t < 4; ++t) afr[t] = zb;
  }
  __syncthreads();

  f32x4 acc[4];
  const f32x4 zf = {0.f, 0.f, 0.f, 0.f};
#pragma unroll
  for (int c = 0; c < 4; ++c) acc[c] = zf;
#pragma unroll
  for (int t = 0; t < 4; ++t)
#pragma unroll
    for (int c = 0; c < 4; ++c) {
      bf16x8 bfr = *(const bf16x8*)&Ws[c * 16 + l15][t * 32 + kg * 8];
      acc[c] = MFMA_BF16(afr[t], bfr, acc[c]);
    }

  // D: row(edge) = kg*4 + reg, col = half*64 + c*16 + l15; store at dst-CSR row
#pragma unroll
  for (int reg = 0; reg < 4; ++reg) {
    if (dpos[reg] >= 0) {
      unsigned short* mp = msg + (size_t)dpos[reg] * HD + half * 64 + l15;
#pragma unroll
      for (int c = 0; c < 4; ++c) mp[c * 16] = f2bf(acc[c][reg]);
    }
  }
}

// ---------------- generic NT GEMM (MFMA bf16): C = epi( A[M,K] @ B[N,K]^T ) ----------------
// EPI 0: +bias; 1: relu(+bias); 2 (DUAL): relu(acc1+b1+gagg(row,col)) + relu(acc2+b2),
//   gagg = cooperative LDS-staged CSR gather-sum of bf16 message rows (wide loads);
//   + BN colsum/colsumsq atomics.
template<bool DUAL, int EPI, bool OBF16>
__global__ __launch_bounds__(256) void gemm_mfma(
    const unsigned short* __restrict__ A, const unsigned short* __restrict__ B1,
    const unsigned short* __restrict__ B2, const float* __restrict__ bias1,
    const float* __restrict__ bias2,
    const unsigned short* __restrict__ msgp, const int* __restrict__ gdoffs,
    const int* __restrict__ gdcount,
    float* __restrict__ Cf, unsigned short* __restrict__ Cb,
    float* __restrict__ colsum, int M, int N, int K) {
  __shared__ __align__(16) unsigned short As[64][40];
  __shared__ __align__(16) unsigned short B1s[64][40];
  __shared__ __align__(16) unsigned short B2s[DUAL ? 64 : 1][40];
  __shared__ float cs[2][64];
  __shared__ float gagg[EPI == 2 ? 64 : 1][EPI == 2 ? 68 : 1];

  int tid = threadIdx.x;
  int lane = tid & 63, w = tid >> 6;
  int wr = w >> 1, wc = w & 1;
  int l15 = lane & 15, kg = lane >> 4;
  int row0 = blockIdx.y * 64, col0 = blockIdx.x * 64;
  int srow = tid >> 2, skc = (tid & 3) * 8;

  // ---- cooperative CSR gather into LDS (EPI 2): thread owns (row, 16-col segment) ----
  if constexpr (EPI == 2) {
    int rw = tid >> 2;              // 0..63 local row
    int cseg = (tid & 3) * 16;      // 16-col segment of this block's 64 cols
    int grow = row0 + rw;
    float fa[16];
#pragma unroll
    for (int k = 0; k < 16; ++k) fa[k] = 0.f;
    if (grow < M) {
      int gb = gdoffs[grow], gd = gdcount[grow];
      const unsigned short* mp = msgp + (size_t)gb * HD + col0 + cseg;
      for (int e = 0; e < gd; ++e, mp += HD) {
        bf16x8 v0 = *(const bf16x8*)mp;
        bf16x8 v1 = *(const bf16x8*)(mp + 8);
#pragma unroll
        for (int k = 0; k < 8; ++k) {
          fa[k]     += bf2f((unsigned short)v0[k]);
          fa[8 + k] += bf2f((unsigned short)v1[k]);
        }
      }
    }
#pragma unroll
    for (int k = 0; k < 16; ++k) gagg[rw][cseg + k] = fa[k];
  }

  f32x4 acc1[2][2], acc2[2][2];
  const f32x4 zf = {0.f, 0.f, 0.f, 0.f};
  const bf16x8 zb = {0, 0, 0, 0, 0, 0, 0, 0};
#pragma unroll
  for (int i = 0; i < 2; ++i)
#pragma unroll
    for (int j = 0; j < 2; ++j) { acc1[i][j] = zf; acc2[i][j] = zf; }

  for (int k0 = 0; k0 < K; k0 += 32) {
    {
      int gr = row0 + srow;
      bf16x8 v = zb;
      if (gr < M) v = *(const bf16x8*)(A + (size_t)gr * K + k0 + skc);
      *(bf16x8*)&As[srow][skc] = v;
      *(bf16x8*)&B1s[srow][skc] = *(const bf16x8*)(B1 + (size_t)(col0 + srow) * K + k0 + skc);
      if constexpr (DUAL)
        *(bf16x8*)&B2s[srow][skc] = *(const bf16x8*)(B2 + (size_t)(col0 + srow) * K + k0 + skc);
    }
    __syncthreads();
    bf16x8 af[2], b1f[2];
#pragma unroll
    for (int i = 0; i < 2; ++i) af[i] = *(const bf16x8*)&As[wr * 32 + i * 16 + l15][kg * 8];
#pragma unroll
    for (int j = 0; j < 2; ++j) b1f[j] = *(const bf16x8*)&B1s[wc * 32 + j * 16 + l15][kg * 8];
#pragma unroll
    for (int i = 0; i < 2; ++i)
#pragma unroll
      for (int j = 0; j < 2; ++j) acc1[i][j] = MFMA_BF16(af[i], b1f[j], acc1[i][j]);
    if constexpr (DUAL) {
      bf16x8 b2f[2];
#pragma unroll
      for (int j = 0; j < 2; ++j) b2f[j] = *(const bf16x8*)&B2s[wc * 32 + j * 16 + l15][kg * 8];
#pragma unroll
      for (int i = 0; i < 2; ++i)
#pragma unroll
        for (int j = 0; j < 2; ++j) acc2[i][j] = MFMA_BF16(af[i], b2f[j], acc2[i][j]);
    }
    __syncthreads();
  }

  float s[2] = {0.f, 0.f}, sq[2] = {0.f, 0.f};
#pragma unroll
  for (int i = 0; i < 2; ++i)
#pragma unroll
    for (int reg = 0; reg < 4; ++reg) {
      int row = row0 + wr * 32 + i * 16 + kg * 4 + reg;
      if (row < M) {
        int lrow = wr * 32 + i * 16 + kg * 4 + reg;
#pragma unroll
        for (int j = 0; j < 2; ++j) {
          int col = col0 + wc * 32 + j * 16 + l15;
          float v = acc1[i][j][reg];
          if constexpr (EPI == 2) {
            float g = gagg[lrow][wc * 32 + j * 16 + l15];
            v = reluf(v + bias1[col] + g) + reluf(acc2[i][j][reg] + bias2[col]);
            Cf[(size_t)row * N + col] = v;
            s[j] += v; sq[j] += v * v;
          } else {
            v += bias1[col];
            if constexpr (EPI == 1) v = reluf(v);
            if constexpr (OBF16) Cb[(size_t)row * N + col] = f2bf(v);
            else Cf[(size_t)row * N + col] = v;
          }
        }
      }
    }
  if constexpr (EPI == 2) {
    __syncthreads();
    if (tid < 128) ((float*)cs)[tid] = 0.f;
    __syncthreads();
#pragma unroll
    for (int j = 0; j < 2; ++j) {
      int lc = wc * 32 + j * 16 + l15;
      atomicAdd(&cs[0][lc], s[j]);
      atomicAdd(&cs[1][lc], sq[j]);
    }
    __syncthreads();
    if (tid < 64) {
      atomicAdd(&colsum[col0 + tid], cs[0][tid]);
      atomicAdd(&colsum[HD + col0 + tid], cs[1][tid]);
    }
  }
}

// ---------------- BatchNorm apply (layer 1 only: writes bf16 h for next layer) ----------------
__global__ void bn_apply_bf16(const float* __restrict__ h, unsigned short* __restrict__ hb,
                              const float* __restrict__ colsum, const float* __restrict__ gamma,
                              const float* __restrict__ beta, int M) {
  int i = blockIdx.x * blockDim.x + threadIdx.x;
  if (i >= M * (HD / 4)) return;
  int c0 = (i & 31) * 4;
  float invM = 1.f / (float)M;
  float4 v = ((const float4*)h)[i];
  float r[4] = {v.x, v.y, v.z, v.w};
#pragma unroll
  for (int j = 0; j < 4; ++j) {
    int c = c0 + j;
    float mu = colsum[c] * invM;
    float var = colsum[HD + c] * invM - mu * mu;
    r[j] = (r[j] - mu) * rsqrtf(var + 1e-5f) * gamma[c] + beta[c];
  }
  ushort4 o;
  o.x = f2bf(r[0]); o.y = f2bf(r[1]); o.z = f2bf(r[2]); o.w = f2bf(r[3]);
  ((ushort4*)hb)[i] = o;
}

// --------- unified readout: graph contiguous-range mean + motif CSR mean, + BN affine ---------
__global__ __launch_bounds__(256) void readout_norm(
    const float* __restrict__ h, const int* __restrict__ gstart,
    const int* __restrict__ nidx, const int* __restrict__ moffs,
    const int* __restrict__ mcount,
    const float* __restrict__ colsum, const float* __restrict__ gamma,
    const float* __restrict__ beta, float invM,
    float* __restrict__ out_gf, unsigned short* __restrict__ headin, int NGr, int NMr) {
  int row = blockIdx.x * 2 + (threadIdx.x >> 7);
  if (row >= NGr + NMr) return;
  int c = threadIdx.x & 127;
  float mu = colsum[c] * invM;
  float var = colsum[HD + c] * invM - mu * mu;
  float sc = gamma[c] * rsqrtf(var + 1e-5f);
  float sh = beta[c] - mu * sc;
  if (row < NGr) {
    int b = gstart[row], e2 = gstart[row + 1];
    float acc = 0.f;
    for (int n = b; n < e2; ++n) acc += h[(size_t)n * HD + c];
    float v = (e2 > b) ? (acc / (float)(e2 - b)) * sc + sh : 0.f;
    out_gf[(size_t)row * HD + c] = v;
    headin[(size_t)row * HD + c] = f2bf(v);
  } else {
    int m = row - NGr;
    int deg = mcount[m], base = moffs[m];
    float acc = 0.f;
    for (int j = 0; j < deg; ++j) acc += h[(size_t)nidx[base + j] * HD + c];
    float v = (deg > 0) ? (acc / (float)deg) * sc + sh : 0.f;
    if (m > 0) headin[(size_t)(NGr + m - 1) * HD + c] = f2bf(v);
  }
}

extern "C" void kernel_launch(void* const* d_in, const int* in_sizes, int n_in,
                              void* d_out, int out_size, void* d_ws, size_t ws_size,
                              hipStream_t stream) {
  const float* x0     = (const float*)d_in[0];
  const int*   src    = (const int*)d_in[1];
  const int*   dst    = (const int*)d_in[2];
  const int*   etype  = (const int*)d_in[3];
  const int*   gids   = (const int*)d_in[4];
  const int*   mids   = (const int*)d_in[5];
  const float* W1     = (const float*)d_in[6];
  const float* loopW1 = (const float*)d_in[7];
  const float* b1     = (const float*)d_in[8];
  const float* resW1  = (const float*)d_in[9];
  const float* resb1  = (const float*)d_in[10];
  const float* g1     = (const float*)d_in[11];
  const float* be1    = (const float*)d_in[12];
  const float* W2     = (const float*)d_in[13];
  const float* loopW2 = (const float*)d_in[14];
  const float* b2     = (const float*)d_in[15];
  const float* resW2  = (const float*)d_in[16];
  const float* resb2  = (const float*)d_in[17];
  const float* g2     = (const float*)d_in[18];
  const float* be2    = (const float*)d_in[19];
  const float* featW  = (const float*)d_in[20];
  const float* featb  = (const float*)d_in[21];
  const float* mW1    = (const float*)d_in[22];
  const float* mb1    = (const float*)d_in[23];
  const float* mW2    = (const float*)d_in[24];
  const float* mb2    = (const float*)d_in[25];

  const int N = in_sizes[0] / HD;   // 30000
  const int E = in_sizes[1];        // 90000
  const int NG = 1500, NM = 6001, FFN = 512, OUT2 = 256;
  const int NCH = (E + 63) / 64 + NREL;
  const int NHD = N * HD;
  const int NHEAD = NG + NM - 1;    // 7500

  float* ws = (float*)d_ws;
  size_t off = 0;
  auto alloc = [&](size_t n) { float* p = ws + off; off += (n + 63) & ~((size_t)63); return p; };
  float* hbuf  = alloc(NHD);
  unsigned short* msg = (unsigned short*)alloc((size_t)E * HD / 2);  // bf16 msgs, dst-CSR order
  unsigned short* xb    = (unsigned short*)alloc(NHD / 2);
  unsigned short* W1tb  = (unsigned short*)alloc((size_t)NREL * HD * HD / 2);
  unsigned short* W2tb  = (unsigned short*)alloc((size_t)NREL * HD * HD / 2);
  unsigned short* lwT1b = (unsigned short*)alloc(HD * HD / 2);
  unsigned short* lwT2b = (unsigned short*)alloc(HD * HD / 2);
  unsigned short* rW1b  = (unsigned short*)alloc(HD * HD / 2);
  unsigned short* rW2b  = (unsigned short*)alloc(HD * HD / 2);
  unsigned short* featWb= (unsigned short*)alloc(FFN * HD / 2);
  unsigned short* mW1b  = (unsigned short*)alloc(FFN * FFN / 2);
  unsigned short* mW2b  = (unsigned short*)alloc(OUT2 * FFN / 2);
  unsigned short* headin= (unsigned short*)alloc((size_t)NHEAD * HD / 2);
  int* offs   = (int*)alloc(NREL + 1);
  int* doffs  = (int*)alloc(N);
  int* moffs  = (int*)alloc(NM);
  int* p0     = (int*)alloc(64);
  int* p1     = (int*)alloc(64);
  int* nidx   = (int*)alloc(N);
  int* gstart = (int*)alloc(NG + 1);   // fully written by scatter_all
  // ---- zero-init span (ONE memset)
  size_t zero_start = off;
  int* counts  = (int*)alloc(NREL);
  int* cursor  = (int*)alloc(NREL);
  int* dcount  = (int*)alloc(N);
  int* dcursor = (int*)alloc(N);
  int* mcount  = (int*)alloc(NM);
  int* mcursor = (int*)alloc(NM);
  float* colsum1 = alloc(2 * HD);
  float* colsum2 = alloc(2 * HD);
  size_t zero_end = off;
  // ---- 0xFF span (ONE memset): chunk_rel, ssrc, sdpos
  size_t ff_start = off;
  int* chunk_rel = (int*)alloc(NCH);
  int* ssrc      = (int*)alloc((size_t)NCH * 64);
  int* sdpos     = (int*)alloc((size_t)NCH * 64);
  size_t ff_end = off;
  // head intermediates alias msg (dead after layer-2 dual GEMM): 15.4MB < 23MB msg span
  unsigned short* fbuf_b = msg;
  unsigned short* obuf_b = msg + (size_t)NHEAD * FFN;

  float* out_gf = (float*)d_out;
  float* out_gl = out_gf + (size_t)NG * HD;

  dim3 blk(256);
  const int nb0 = (N + SCB - 1) / SCB;    // 30
  const int nb1 = (NM + SCB - 1) / SCB;   // 6

  // ---- one fused prep kernel: transposes + casts ----
  PrepArgs pa{};
  pa.W1 = W1; pa.W2 = W2; pa.lw1 = loopW1; pa.lw2 = loopW2;
  pa.W1t = W1tb; pa.W2t = W2tb; pa.l1t = lwT1b; pa.l2t = lwT2b;
  pa.csrc[0] = x0;    pa.cdst[0] = xb;     pa.cn4[0] = NHD / 4;
  pa.csrc[1] = resW1; pa.cdst[1] = rW1b;   pa.cn4[1] = HD * HD / 4;
  pa.csrc[2] = resW2; pa.cdst[2] = rW2b;   pa.cn4[2] = HD * HD / 4;
  pa.csrc[3] = featW; pa.cdst[3] = featWb; pa.cn4[3] = FFN * HD / 4;
  pa.csrc[4] = mW1;   pa.cdst[4] = mW1b;   pa.cn4[4] = FFN * FFN / 4;
  pa.csrc[5] = mW2;   pa.cdst[5] = mW2b;   pa.cn4[5] = OUT2 * FFN / 4;
  pa.total4 = pa.cn4[0] + pa.cn4[1] + pa.cn4[2] + pa.cn4[3] + pa.cn4[4] + pa.cn4[5];
  int prepBlocks = NTB + (pa.total4 + 255) / 256;
  prep_all<<<prepBlocks, blk, 0, stream>>>(pa);

  // ---- init + CSR build: 2 memsets + 4 kernels ----
  hipMemsetAsync(ws + zero_start, 0, (zero_end - zero_start) * sizeof(float), stream);
  hipMemsetAsync(ws + ff_start, 0xFF, (ff_end - ff_start) * sizeof(float), stream);
  int histBlocks = (E + N + 255) / 256;
  hist_all<<<histBlocks, blk, 0, stream>>>(etype, dst, mids, counts, dcount, mcount, E, N);
  scan_blocks<<<dim3(nb0, 3), SCB, 0, stream>>>(counts, offs, dcount, doffs, p0, N,
                                                mcount, moffs, p1, NM);
  scan_addback2<<<dim3(nb0, 2), SCB, 0, stream>>>(doffs, p0, N, moffs, p1, NM);
  scatter_all<<<histBlocks, blk, 0, stream>>>(src, dst, etype, mids, gids, offs, cursor,
                                              doffs, dcursor, moffs, mcursor,
                                              ssrc, chunk_rel, sdpos, nidx, gstart, E, N, NG);

  dim3 gridDual(HD / 64, (N + 63) / 64);
  dim3 gridEdge(NCH, 2);
  int bnBlocks = (N * (HD / 4) + 255) / 256;

  // ---------------- layer 1 (gather LDS-staged in dual GEMM) ----------------
  edge_gemm_msg<<<gridEdge, blk, 0, stream>>>(xb, W1tb, ssrc, sdpos, chunk_rel, msg);
  gemm_mfma<true, 2, false><<<gridDual, blk, 0, stream>>>(
      xb, lwT1b, rW1b, b1, resb1, msg, doffs, dcount, hbuf, nullptr, colsum1, N, HD, HD);
  bn_apply_bf16<<<bnBlocks, blk, 0, stream>>>(hbuf, xb, colsum1, g1, be1, N);  // -> h1 bf16

  // ---------------- layer 2 (BN folded into readout_norm) ----------------
  edge_gemm_msg<<<gridEdge, blk, 0, stream>>>(xb, W2tb, ssrc, sdpos, chunk_rel, msg);
  gemm_mfma<true, 2, false><<<gridDual, blk, 0, stream>>>(
      xb, lwT2b, rW2b, b2, resb2, msg, doffs, dcount, hbuf, nullptr, colsum2, N, HD, HD);

  // ---------------- readout (graph ranges + motif CSR, one kernel) ----------------
  float invM = 1.f / (float)N;
  readout_norm<<<(NG + NM + 1) / 2, blk, 0, stream>>>(
      hbuf, gstart, nidx, moffs, mcount, colsum2, g2, be2, invM, out_gf, headin, NG, NM);

  // ---- unified head over 7500 rows (last GEMM writes straight to d_out) ----
  dim3 gA(FFN / 64, (NHEAD + 63) / 64);
  gemm_mfma<false, 0, true><<<gA, blk, 0, stream>>>(
      headin, featWb, nullptr, featb, nullptr, nullptr, nullptr, nullptr, nullptr, fbuf_b, nullptr, NHEAD, FFN, HD);
  gemm_mfma<false, 1, true><<<gA, blk, 0, stream>>>(
      fbuf_b, mW1b, nullptr, mb1, nullptr, nullptr, nullptr, nullptr, nullptr, obuf_b, nullptr, NHEAD, FFN, FFN);
  dim3 gC(OUT2 / 64, (NHEAD + 63) / 64);
  gemm_mfma<false, 0, false><<<gC, blk, 0, stream>>>(
      obuf_b, mW2b, nullptr, mb2, nullptr, nullptr, nullptr, nullptr, out_gl, nullptr, nullptr, NHEAD, OUT2, FFN);
}